// Round 6
// baseline (156.643 us; speedup 1.0000x reference)
//
#include <hip/hip_runtime.h>
#include <hip/hip_bf16.h>

// OutlookAttention: B=8,H=56,W=56,C=192,heads=6,K=3,pad=1 — fp32 in/out
constexpr int NH = 56, NW = 56, NC = 192, AJ = 486;
constexpr int HWP = NH * NW;   // 3136
constexpr int NPIX = 8 * HWP;  // 25088
constexpr float SCALE = 0.17677669529663687f;  // 1/sqrt(32)

typedef __bf16 bf16x8 __attribute__((ext_vector_type(8)));
typedef float f32x4 __attribute__((ext_vector_type(4)));

__device__ __forceinline__ void gload16(const void* g, void* l) {
  __builtin_amdgcn_global_load_lds(
      (const __attribute__((address_space(1))) void*)g,
      (__attribute__((address_space(3))) void*)l, 16, 0, 0);
}

// ---------------------------------------------------------------------------
// P0: weights -> bf16 [n][k] transposed (Wat zero-padded to 512 rows);
//     x -> bf16 (xb), 8 elems/thread.
// ---------------------------------------------------------------------------
__global__ __launch_bounds__(256) void k_prep2(const float* __restrict__ x,
                                               const float* __restrict__ Wv,
                                               const float* __restrict__ Wa,
                                               const float* __restrict__ Wp,
                                               __bf16* __restrict__ xb,
                                               __bf16* __restrict__ Wvt,
                                               __bf16* __restrict__ Wat,
                                               __bf16* __restrict__ Wpt) {
  const int bid = blockIdx.x;
  if (bid < 144) {  // Wvt/Wpt: 192x192
    const int i = bid * 256 + threadIdx.x;
    const int n = i / 192, k = i - n * 192;
    Wvt[i] = (__bf16)Wv[k * 192 + n];
    Wpt[i] = (__bf16)Wp[k * 192 + n];
  } else if (bid < 528) {  // Wat: 512x192 (pad rows 486..511 zero)
    const int i = (bid - 144) * 256 + threadIdx.x;
    const int n = i / 192, k = i - n * 192;
    Wat[i] = (n < 486) ? (__bf16)Wa[k * 486 + n] : (__bf16)0.f;
  } else {  // xb: 4,816,896 elems, 8/thread
    const size_t i = (size_t)(bid - 528) * 256 + threadIdx.x;
    const float* src = x + i * 8;
    const float4 f0 = *(const float4*)src;
    const float4 f1 = *(const float4*)(src + 4);
    bf16x8 o8;
    o8[0] = (__bf16)f0.x; o8[1] = (__bf16)f0.y;
    o8[2] = (__bf16)f0.z; o8[3] = (__bf16)f0.w;
    o8[4] = (__bf16)f1.x; o8[5] = (__bf16)f1.y;
    o8[6] = (__bf16)f1.z; o8[7] = (__bf16)f1.w;
    *(bf16x8*)(xb + i * 8) = o8;
  }
}

// ---------------------------------------------------------------------------
// Fused v-GEMM + logits-GEMM (one dispatch, block-uniform mode branch).
// by<3 (V):  C1[pix][ch] = xb @ Wvt^T. Tile 128(pix) x 64(ch). bf16 out.
// by>=3 (L): lgT[j][pix] = (Wat @ xb^T + ba)*SCALE. Tile 128(j) x 128(pix).
// 256 thr = 4 waves in 2x2. global_load_lds staging, BK=32, 6 K-iters.
// ---------------------------------------------------------------------------
__global__ __launch_bounds__(256) void k_mm(const __bf16* __restrict__ xb,
                                            const __bf16* __restrict__ Wvt,
                                            const __bf16* __restrict__ Wat,
                                            const float* __restrict__ ba,
                                            __bf16* __restrict__ v,
                                            __bf16* __restrict__ lgT) {
  __shared__ __bf16 As[128 * 32];
  __shared__ __bf16 Bs[128 * 32];
  const int t = threadIdx.x, lane = t & 63, w = t >> 6;
  const int wm = w >> 1, wn = w & 1;
  const bool vmode = (blockIdx.y < 3);
  const __bf16* Aptr = vmode ? xb + (size_t)(blockIdx.x * 128) * 192
                             : Wat + (size_t)((blockIdx.y - 3) * 128) * 192;
  const __bf16* Bptr = vmode ? Wvt + (size_t)(blockIdx.y * 64) * 192
                             : xb + (size_t)(blockIdx.x * 128) * 192;

  f32x4 acc[4][4];
  #pragma unroll
  for (int mi = 0; mi < 4; ++mi)
    #pragma unroll
    for (int nj = 0; nj < 4; ++nj) acc[mi][nj] = (f32x4){0.f, 0.f, 0.f, 0.f};

  for (int k0 = 0; k0 < 192; k0 += 32) {
    __syncthreads();
    #pragma unroll
    for (int i = 0; i < 2; ++i) {  // A: 128 rows x 32 k = 512 chunks
      const int c = i * 256 + w * 64 + lane;
      gload16(Aptr + (size_t)(c >> 2) * 192 + k0 + (c & 3) * 8,
              &As[(i * 256 + w * 64) * 8]);
    }
    {  // B: first 64 rows (both modes)
      const int c = w * 64 + lane;
      gload16(Bptr + (size_t)(c >> 2) * 192 + k0 + (c & 3) * 8,
              &Bs[(w * 64) * 8]);
    }
    if (!vmode) {  // B rows 64..127 (logits mode only)
      const int c = 256 + w * 64 + lane;
      gload16(Bptr + (size_t)(c >> 2) * 192 + k0 + (c & 3) * 8,
              &Bs[(256 + w * 64) * 8]);
    }
    __syncthreads();
    bf16x8 af[4], bfr[4];
    #pragma unroll
    for (int mi = 0; mi < 4; ++mi)
      af[mi] = *(const bf16x8*)&As[(wm * 64 + mi * 16 + (lane & 15)) * 32 + (lane >> 4) * 8];
    if (vmode) {
      #pragma unroll
      for (int nj = 0; nj < 2; ++nj)
        bfr[nj] = *(const bf16x8*)&Bs[(wn * 32 + nj * 16 + (lane & 15)) * 32 + (lane >> 4) * 8];
      #pragma unroll
      for (int mi = 0; mi < 4; ++mi)
        #pragma unroll
        for (int nj = 0; nj < 2; ++nj)
          acc[mi][nj] = __builtin_amdgcn_mfma_f32_16x16x32_bf16(af[mi], bfr[nj], acc[mi][nj], 0, 0, 0);
    } else {
      #pragma unroll
      for (int nj = 0; nj < 4; ++nj)
        bfr[nj] = *(const bf16x8*)&Bs[(wn * 64 + nj * 16 + (lane & 15)) * 32 + (lane >> 4) * 8];
      #pragma unroll
      for (int mi = 0; mi < 4; ++mi)
        #pragma unroll
        for (int nj = 0; nj < 4; ++nj)
          acc[mi][nj] = __builtin_amdgcn_mfma_f32_16x16x32_bf16(af[mi], bfr[nj], acc[mi][nj], 0, 0, 0);
    }
  }
  const int col_l = lane & 15, rq4 = (lane >> 4) * 4;
  if (vmode) {
    #pragma unroll
    for (int nj = 0; nj < 2; ++nj) {
      const int gn = blockIdx.y * 64 + wn * 32 + nj * 16 + col_l;  // ch
      #pragma unroll
      for (int mi = 0; mi < 4; ++mi) {
        const int gm = blockIdx.x * 128 + wm * 64 + mi * 16 + rq4;  // pix
        #pragma unroll
        for (int r = 0; r < 4; ++r)
          v[(size_t)(gm + r) * 192 + gn] = (__bf16)acc[mi][nj][r];
      }
    }
  } else {
    #pragma unroll
    for (int nj = 0; nj < 4; ++nj) {
      const int gn = blockIdx.x * 128 + wn * 64 + nj * 16 + col_l;  // pix
      #pragma unroll
      for (int mi = 0; mi < 4; ++mi) {
        const int gmb = (blockIdx.y - 3) * 128 + wm * 64 + mi * 16 + rq4;
        #pragma unroll
        for (int r = 0; r < 4; ++r) {
          const int gm = gmb + r;  // j
          if (gm < 486)
            lgT[(size_t)gm * NPIX + gn] = (__bf16)((acc[mi][nj][r] + ba[gm]) * SCALE);
        }
      }
    }
  }
}

// ---------------------------------------------------------------------------
// Out GEMM: C[pix][ch] f32 = o @ Wpt^T + bp. Tile 128x64, grid (196,3).
// ---------------------------------------------------------------------------
__global__ __launch_bounds__(256) void k_gemm_out(const __bf16* __restrict__ A,
                                                  const __bf16* __restrict__ Bt,
                                                  const float* __restrict__ bias,
                                                  float* __restrict__ C) {
  __shared__ __bf16 As[128 * 32];
  __shared__ __bf16 Bs[64 * 32];
  const int m0 = blockIdx.x * 128, n0 = blockIdx.y * 64;
  const int t = threadIdx.x, lane = t & 63, w = t >> 6;
  const int wm = w >> 1, wn = w & 1;
  f32x4 acc[4][2];
  #pragma unroll
  for (int mi = 0; mi < 4; ++mi)
    #pragma unroll
    for (int nj = 0; nj < 2; ++nj) acc[mi][nj] = (f32x4){0.f, 0.f, 0.f, 0.f};

  for (int k0 = 0; k0 < 192; k0 += 32) {
    __syncthreads();
    #pragma unroll
    for (int i = 0; i < 2; ++i) {
      const int c = i * 256 + w * 64 + lane;
      gload16(A + (size_t)(m0 + (c >> 2)) * 192 + k0 + (c & 3) * 8,
              &As[(i * 256 + w * 64) * 8]);
    }
    {
      const int c = w * 64 + lane;
      gload16(Bt + (size_t)(n0 + (c >> 2)) * 192 + k0 + (c & 3) * 8,
              &Bs[(w * 64) * 8]);
    }
    __syncthreads();
    bf16x8 af[4], bfr[2];
    #pragma unroll
    for (int mi = 0; mi < 4; ++mi)
      af[mi] = *(const bf16x8*)&As[(wm * 64 + mi * 16 + (lane & 15)) * 32 + (lane >> 4) * 8];
    #pragma unroll
    for (int nj = 0; nj < 2; ++nj)
      bfr[nj] = *(const bf16x8*)&Bs[(wn * 32 + nj * 16 + (lane & 15)) * 32 + (lane >> 4) * 8];
    #pragma unroll
    for (int mi = 0; mi < 4; ++mi)
      #pragma unroll
      for (int nj = 0; nj < 2; ++nj)
        acc[mi][nj] = __builtin_amdgcn_mfma_f32_16x16x32_bf16(af[mi], bfr[nj], acc[mi][nj], 0, 0, 0);
  }
  const int col_l = lane & 15, rq4 = (lane >> 4) * 4;
  #pragma unroll
  for (int nj = 0; nj < 2; ++nj) {
    const int gn = n0 + wn * 32 + nj * 16 + col_l;
    const float bv = bias[gn];
    #pragma unroll
    for (int mi = 0; mi < 4; ++mi) {
      const int gm = m0 + wm * 64 + mi * 16 + rq4;
      #pragma unroll
      for (int r = 0; r < 4; ++r)
        C[(size_t)(gm + r) * 192 + gn] = acc[mi][nj][r] + bv;
    }
  }
}

// ---------------------------------------------------------------------------
// K-coef: fused softmax + delta-collapse. thread = out pixel, blockIdx.y = head.
// ---------------------------------------------------------------------------
__global__ __launch_bounds__(256) void k_coef(const __bf16* __restrict__ lgT,
                                              __bf16* __restrict__ wcT) {
  const int p = blockIdx.x * 256 + threadIdx.x;
  const int head = blockIdx.y;
  const int b = p / HWP;
  const int yx = p - b * HWP;
  const int y = yx / NW, x = yx - y * NW;

  float wc[25];
  #pragma unroll
  for (int c = 0; c < 25; ++c) wc[c] = 0.f;

  #pragma unroll
  for (int ki = 0; ki < 3; ++ki) {
    const int h = y - ki + 1;
    if ((unsigned)h >= (unsigned)NH) continue;
    #pragma unroll
    for (int kj = 0; kj < 3; ++kj) {
      const int ww = x - kj + 1;
      if ((unsigned)ww >= (unsigned)NW) continue;
      const int src = b * HWP + h * NW + ww;
      const size_t base = (size_t)((head * 9 + ki * 3 + kj) * 9) * NPIX + src;
      float lt[9];
      #pragma unroll
      for (int l = 0; l < 9; ++l) lt[l] = (float)lgT[base + (size_t)l * NPIX];
      float m = lt[0];
      #pragma unroll
      for (int l = 1; l < 9; ++l) m = fmaxf(m, lt[l]);
      float s = 0.f;
      #pragma unroll
      for (int l = 0; l < 9; ++l) { lt[l] = __expf(lt[l] - m); s += lt[l]; }
      const float inv = 1.f / s;
      #pragma unroll
      for (int l = 0; l < 9; ++l) {
        const int li = l / 3, lj = l - li * 3;
        wc[(li - ki + 2) * 5 + (lj - kj + 2)] += lt[l] * inv;
      }
    }
  }
  #pragma unroll
  for (int c = 0; c < 25; ++c)
    wcT[(size_t)(head * 25 + c) * NPIX + p] = (__bf16)wc[c];
}

// ---------------------------------------------------------------------------
// K-att2: gather. 8 pixels/block (same row), 192 thr = channels.
// ---------------------------------------------------------------------------
__global__ __launch_bounds__(192) void k_att2(const __bf16* __restrict__ v,
                                              const __bf16* __restrict__ wcT,
                                              __bf16* __restrict__ o) {
  const int p0 = blockIdx.x * 8;
  const int bb = p0 / HWP;
  const int yx0 = p0 - bb * HWP;
  const int y = yx0 / NW, x0 = yx0 - y * NW;
  const int t = threadIdx.x;

  __shared__ __bf16 vs[60][192];
  __shared__ float wcs[8][6][28];

  for (int i = t; i < 1440; i += 192) {
    const int cell = i / 24, ck = i - cell * 24;
    const int di = cell / 12, col = cell - di * 12;
    const int yy = y + di - 2, xx = x0 + col - 2;
    bf16x8 val;
    #pragma unroll
    for (int j = 0; j < 8; ++j) val[j] = (__bf16)0.f;
    if ((unsigned)yy < (unsigned)NH && (unsigned)xx < (unsigned)NW)
      val = *(const bf16x8*)&v[(size_t)(bb * HWP + yy * NW + xx) * 192 + ck * 8];
    *(bf16x8*)&vs[cell][ck * 8] = val;
  }
  if (t < 150) {
    const int head = t / 25, cc = t - head * 25;
    const bf16x8 w8 = *(const bf16x8*)&wcT[(size_t)t * NPIX + p0];
    #pragma unroll
    for (int q = 0; q < 8; ++q) wcs[q][head][cc] = (float)w8[q];
  }
  __syncthreads();

  const int ch = t, head = ch >> 5;
  float vr[5][12];
  #pragma unroll
  for (int di = 0; di < 5; ++di)
    #pragma unroll
    for (int col = 0; col < 12; ++col) vr[di][col] = (float)vs[di * 12 + col][ch];
  #pragma unroll
  for (int q = 0; q < 8; ++q) {
    float coef[25];
    #pragma unroll
    for (int i = 0; i < 6; ++i)
      *(float4*)&coef[i * 4] = *(const float4*)&wcs[q][head][i * 4];
    coef[24] = wcs[q][head][24];
    float s = 0.f;
    #pragma unroll
    for (int di = 0; di < 5; ++di)
      #pragma unroll
      for (int dj = 0; dj < 5; ++dj) s += coef[di * 5 + dj] * vr[di][q + dj];
    o[(size_t)(p0 + q) * 192 + ch] = (__bf16)s;
  }
}

// ---------------------------------------------------------------------------
extern "C" void kernel_launch(void* const* d_in, const int* in_sizes, int n_in,
                              void* d_out, int out_size, void* d_ws,
                              size_t ws_size, hipStream_t stream) {
  (void)in_sizes; (void)n_in; (void)out_size; (void)ws_size;
  const float* x  = (const float*)d_in[0];
  const float* Wv = (const float*)d_in[1];
  const float* Wa = (const float*)d_in[2];
  const float* ba = (const float*)d_in[3];
  const float* Wp = (const float*)d_in[4];
  const float* bp = (const float*)d_in[5];

  char* ws = (char*)d_ws;  // ws_size = 256 MiB; we use 51.5 MB
  __bf16* Wvt = (__bf16*)(ws);                  //     73,728 B
  __bf16* Wat = (__bf16*)(ws + 73728);          //    196,608 B (512x192, padded)
  __bf16* Wpt = (__bf16*)(ws + 270336);         //     73,728 B
  __bf16* xb  = (__bf16*)(ws + 344064);         //  9,633,792 B
  __bf16* v_ws = (__bf16*)(ws + 9977856);       //  9,633,792 B
  __bf16* lgT = (__bf16*)(ws + 19611648);       // 24,385,536 B (486 x 25088)
  __bf16* wcT = (__bf16*)(ws + 43997184);       //  7,526,400 B (150 x 25088)
  __bf16* o_ws = (__bf16*)(ws + 19611648);      // aliases lgT (dead after k_coef)

  k_prep2<<<2880, 256, 0, stream>>>(x, Wv, Wa, Wp, xb, Wvt, Wat, Wpt);
  k_mm<<<dim3(196, 7), 256, 0, stream>>>(xb, Wvt, Wat, ba, v_ws, lgT);
  k_coef<<<dim3(98, 6), 256, 0, stream>>>(lgT, wcT);
  k_att2<<<NPIX / 8, 192, 0, stream>>>(v_ws, wcT, o_ws);
  k_gemm_out<<<dim3(196, 3), 256, 0, stream>>>(o_ws, Wpt, bp, (float*)d_out);
}

// Round 8
// 146.360 us; speedup vs baseline: 1.0703x; 1.0703x over previous
//
#include <hip/hip_runtime.h>
#include <hip/hip_bf16.h>

// OutlookAttention: B=8,H=56,W=56,C=192,heads=6,K=3,pad=1 — fp32 in/out
constexpr int NH = 56, NW = 56, NC = 192, AJ = 486;
constexpr int HWP = NH * NW;   // 3136
constexpr int NPIX = 8 * HWP;  // 25088
constexpr float SCALE = 0.17677669529663687f;  // 1/sqrt(32)
constexpr int TS = 12288;  // elems per 64-row tile: 6 strips * 64 rows * 32 k

typedef __bf16 bf16x8 __attribute__((ext_vector_type(8)));
typedef float f32x4 __attribute__((ext_vector_type(4)));

__device__ __forceinline__ void gload16(const void* g, void* l) {
  __builtin_amdgcn_global_load_lds(
      (const __attribute__((address_space(1))) void*)g,
      (__attribute__((address_space(3))) void*)l, 16, 0, 0);
}

// tiled offset for (row, k) in a [tile64][strip6][row64][k32] operand
__device__ __forceinline__ size_t toff(int row, int k) {
  return (size_t)(row >> 6) * TS + (k >> 5) * 2048 + (row & 63) * 32 + (k & 31);
}

// ---------------------------------------------------------------------------
// P0: weights -> bf16 transposed [n][k] in k-strip tiled layout (Wat padded to
// 512 rows); x -> bf16 xb, tiled. 8 elems/thread for xb.
// ---------------------------------------------------------------------------
__global__ __launch_bounds__(256) void k_prep3(const float* __restrict__ x,
                                               const float* __restrict__ Wv,
                                               const float* __restrict__ Wa,
                                               const float* __restrict__ Wp,
                                               __bf16* __restrict__ xb,
                                               __bf16* __restrict__ Wvt,
                                               __bf16* __restrict__ Wat,
                                               __bf16* __restrict__ Wpt) {
  const int bid = blockIdx.x;
  if (bid < 144) {  // Wvt/Wpt: 192x192 transposed+tiled
    const int i = bid * 256 + threadIdx.x;
    const int n = i / 192, k = i - n * 192;
    const size_t d = toff(n, k);
    Wvt[d] = (__bf16)Wv[k * 192 + n];
    Wpt[d] = (__bf16)Wp[k * 192 + n];
  } else if (bid < 528) {  // Wat: 512x192 (rows 486..511 zero), tiled
    const int i = (bid - 144) * 256 + threadIdx.x;
    const int n = i / 192, k = i - n * 192;
    Wat[toff(n, k)] = (n < 486) ? (__bf16)Wa[k * 486 + n] : (__bf16)0.f;
  } else {  // xb: 602112 chunks of 8
    const size_t i = (size_t)(bid - 528) * 256 + threadIdx.x;
    const int pix = (int)(i / 24), c8 = (int)(i % 24) * 8;
    const float* src = x + (size_t)pix * 192 + c8;
    const float4 f0 = *(const float4*)src;
    const float4 f1 = *(const float4*)(src + 4);
    bf16x8 o8;
    o8[0] = (__bf16)f0.x; o8[1] = (__bf16)f0.y;
    o8[2] = (__bf16)f0.z; o8[3] = (__bf16)f0.w;
    o8[4] = (__bf16)f1.x; o8[5] = (__bf16)f1.y;
    o8[6] = (__bf16)f1.z; o8[7] = (__bf16)f1.w;
    *(bf16x8*)(xb + toff(pix, c8)) = o8;
  }
}

// ---------------------------------------------------------------------------
// Single-shot GEMM: 64x64 tile, WHOLE K=192 staged once, ONE barrier.
// LDS layout per operand: [strip6][row64][k32] (conflict-free, matches the
// linear global_load_lds copy of a tiled operand). 4 waves 2x2, wave 32x32.
// MODE 0: v[pix][ch] bf16 = xb @ Wvt^T           (grid 392 x 3)
// MODE 1: lgT[j][pix] bf16 = (Wat @ xb^T+ba)*SC  (grid 392 x 8, y=j-tile)
// MODE 2: out[pix][ch] f32 = o @ Wpt^T + bp      (grid 392 x 3)
// ---------------------------------------------------------------------------
template <int MODE>
__global__ __launch_bounds__(256) void k_gemm1(const __bf16* __restrict__ At,
                                               const __bf16* __restrict__ Bt,
                                               const float* __restrict__ bias,
                                               void* __restrict__ C) {
  __shared__ __bf16 As[64 * 192];
  __shared__ __bf16 Bs[64 * 192];
  const int t = threadIdx.x, lane = t & 63, w = t >> 6;
  const int wm = w >> 1, wn = w & 1;
  const int a_tile = (MODE == 1) ? blockIdx.y : blockIdx.x;
  const int b_tile = (MODE == 1) ? blockIdx.x : blockIdx.y;
  const __bf16* Asrc = At + (size_t)a_tile * TS;
  const __bf16* Bsrc = Bt + (size_t)b_tile * TS;
  // stage the FULL 12288-elem (1536-chunk) operands: 6 iters x 256 thr
  #pragma unroll
  for (int i = 0; i < 6; ++i) {
    const int cb = i * 256 + w * 64;  // wave-uniform chunk base
    gload16(Asrc + (size_t)(cb + lane) * 8, &As[cb * 8]);
    gload16(Bsrc + (size_t)(cb + lane) * 8, &Bs[cb * 8]);
  }
  f32x4 acc[2][2];
  #pragma unroll
  for (int mi = 0; mi < 2; ++mi)
    #pragma unroll
    for (int nj = 0; nj < 2; ++nj) acc[mi][nj] = (f32x4){0.f, 0.f, 0.f, 0.f};
  __syncthreads();  // the ONLY barrier
  #pragma unroll
  for (int ks = 0; ks < 6; ++ks) {
    bf16x8 af[2], bfr[2];
    #pragma unroll
    for (int mi = 0; mi < 2; ++mi)
      af[mi] = *(const bf16x8*)&As[(ks * 64 + wm * 32 + mi * 16 + (lane & 15)) * 32 + (lane >> 4) * 8];
    #pragma unroll
    for (int nj = 0; nj < 2; ++nj)
      bfr[nj] = *(const bf16x8*)&Bs[(ks * 64 + wn * 32 + nj * 16 + (lane & 15)) * 32 + (lane >> 4) * 8];
    #pragma unroll
    for (int mi = 0; mi < 2; ++mi)
      #pragma unroll
      for (int nj = 0; nj < 2; ++nj)
        acc[mi][nj] = __builtin_amdgcn_mfma_f32_16x16x32_bf16(af[mi], bfr[nj], acc[mi][nj], 0, 0, 0);
  }
  // epilogue: C/D layout col=lane&15, row=(lane>>4)*4+r
  const int col_l = lane & 15, rq4 = (lane >> 4) * 4;
  #pragma unroll
  for (int nj = 0; nj < 2; ++nj) {
    const int ln = wn * 32 + nj * 16 + col_l;
    #pragma unroll
    for (int mi = 0; mi < 2; ++mi) {
      const int lm = wm * 32 + mi * 16 + rq4;
      #pragma unroll
      for (int r = 0; r < 4; ++r) {
        const float val = acc[mi][nj][r];
        if (MODE == 0) {
          const int pix = blockIdx.x * 64 + lm + r, ch = blockIdx.y * 64 + ln;
          ((__bf16*)C)[(size_t)pix * 192 + ch] = (__bf16)val;
        } else if (MODE == 1) {
          const int j = blockIdx.y * 64 + lm + r, pix = blockIdx.x * 64 + ln;
          if (j < 486)
            ((__bf16*)C)[(size_t)j * NPIX + pix] = (__bf16)((val + bias[j]) * SCALE);
        } else {
          const int pix = blockIdx.x * 64 + lm + r, ch = blockIdx.y * 64 + ln;
          ((float*)C)[(size_t)pix * 192 + ch] = val + bias[ch];
        }
      }
    }
  }
}

// ---------------------------------------------------------------------------
// K-coef: fused softmax + delta-collapse. thread = out pixel, blockIdx.y = head.
// ---------------------------------------------------------------------------
__global__ __launch_bounds__(256) void k_coef(const __bf16* __restrict__ lgT,
                                              __bf16* __restrict__ wcT) {
  const int p = blockIdx.x * 256 + threadIdx.x;
  const int head = blockIdx.y;
  const int b = p / HWP;
  const int yx = p - b * HWP;
  const int y = yx / NW, x = yx - y * NW;

  float wc[25];
  #pragma unroll
  for (int c = 0; c < 25; ++c) wc[c] = 0.f;

  #pragma unroll
  for (int ki = 0; ki < 3; ++ki) {
    const int h = y - ki + 1;
    if ((unsigned)h >= (unsigned)NH) continue;
    #pragma unroll
    for (int kj = 0; kj < 3; ++kj) {
      const int ww = x - kj + 1;
      if ((unsigned)ww >= (unsigned)NW) continue;
      const int src = b * HWP + h * NW + ww;
      const size_t base = (size_t)((head * 9 + ki * 3 + kj) * 9) * NPIX + src;
      float lt[9];
      #pragma unroll
      for (int l = 0; l < 9; ++l) lt[l] = (float)lgT[base + (size_t)l * NPIX];
      float m = lt[0];
      #pragma unroll
      for (int l = 1; l < 9; ++l) m = fmaxf(m, lt[l]);
      float s = 0.f;
      #pragma unroll
      for (int l = 0; l < 9; ++l) { lt[l] = __expf(lt[l] - m); s += lt[l]; }
      const float inv = 1.f / s;
      #pragma unroll
      for (int l = 0; l < 9; ++l) {
        const int li = l / 3, lj = l - li * 3;
        wc[(li - ki + 2) * 5 + (lj - kj + 2)] += lt[l] * inv;
      }
    }
  }
  #pragma unroll
  for (int c = 0; c < 25; ++c)
    wcT[(size_t)(head * 25 + c) * NPIX + p] = (__bf16)wc[c];
}

// ---------------------------------------------------------------------------
// K-att2: gather. 8 pixels/block (same row), 192 thr = channels.
// Writes o in k-strip TILED layout (ready for MODE-2 GEMM staging).
// ---------------------------------------------------------------------------
__global__ __launch_bounds__(192) void k_att2(const __bf16* __restrict__ v,
                                              const __bf16* __restrict__ wcT,
                                              __bf16* __restrict__ o) {
  const int p0 = blockIdx.x * 8;
  const int bb = p0 / HWP;
  const int yx0 = p0 - bb * HWP;
  const int y = yx0 / NW, x0 = yx0 - y * NW;
  const int t = threadIdx.x;

  __shared__ __bf16 vs[60][192];
  __shared__ float wcs[8][6][28];

  for (int i = t; i < 1440; i += 192) {
    const int cell = i / 24, ck = i - cell * 24;
    const int di = cell / 12, col = cell - di * 12;
    const int yy = y + di - 2, xx = x0 + col - 2;
    bf16x8 val;
    #pragma unroll
    for (int j = 0; j < 8; ++j) val[j] = (__bf16)0.f;
    if ((unsigned)yy < (unsigned)NH && (unsigned)xx < (unsigned)NW)
      val = *(const bf16x8*)&v[(size_t)(bb * HWP + yy * NW + xx) * 192 + ck * 8];
    *(bf16x8*)&vs[cell][ck * 8] = val;
  }
  if (t < 150) {
    const int head = t / 25, cc = t - head * 25;
    const bf16x8 w8 = *(const bf16x8*)&wcT[(size_t)t * NPIX + p0];
    #pragma unroll
    for (int q = 0; q < 8; ++q) wcs[q][head][cc] = (float)w8[q];
  }
  __syncthreads();

  const int ch = t, head = ch >> 5;
  float vr[5][12];
  #pragma unroll
  for (int di = 0; di < 5; ++di)
    #pragma unroll
    for (int col = 0; col < 12; ++col) vr[di][col] = (float)vs[di * 12 + col][ch];
  // tiled store base: p0..p0+7 stay in one 64-row tile (p0 multiple of 8)
  const size_t obase = (size_t)(p0 >> 6) * TS + (ch >> 5) * 2048 + (p0 & 63) * 32 + (ch & 31);
  #pragma unroll
  for (int q = 0; q < 8; ++q) {
    float coef[25];
    #pragma unroll
    for (int i = 0; i < 6; ++i)
      *(float4*)&coef[i * 4] = *(const float4*)&wcs[q][head][i * 4];
    coef[24] = wcs[q][head][24];
    float s = 0.f;
    #pragma unroll
    for (int di = 0; di < 5; ++di)
      #pragma unroll
      for (int dj = 0; dj < 5; ++dj) s += coef[di * 5 + dj] * vr[di][q + dj];
    o[obase + q * 32] = (__bf16)s;
  }
}

// ---------------------------------------------------------------------------
extern "C" void kernel_launch(void* const* d_in, const int* in_sizes, int n_in,
                              void* d_out, int out_size, void* d_ws,
                              size_t ws_size, hipStream_t stream) {
  (void)in_sizes; (void)n_in; (void)out_size; (void)ws_size;
  const float* x  = (const float*)d_in[0];
  const float* Wv = (const float*)d_in[1];
  const float* Wa = (const float*)d_in[2];
  const float* ba = (const float*)d_in[3];
  const float* Wp = (const float*)d_in[4];
  const float* bp = (const float*)d_in[5];

  char* ws = (char*)d_ws;  // ws_size = 256 MiB; we use ~51.5 MB
  __bf16* Wvt = (__bf16*)(ws);                  //     73,728 B (tiled)
  __bf16* Wat = (__bf16*)(ws + 73728);          //    196,608 B (512x192 tiled)
  __bf16* Wpt = (__bf16*)(ws + 270336);         //     73,728 B (tiled)
  __bf16* xb  = (__bf16*)(ws + 344064);         //  9,633,792 B (tiled)
  __bf16* v_ws = (__bf16*)(ws + 9977856);       //  9,633,792 B (pixel-major)
  __bf16* lgT = (__bf16*)(ws + 19611648);       // 24,385,536 B (486 x 25088)
  __bf16* wcT = (__bf16*)(ws + 43997184);       //  7,526,400 B (150 x 25088)
  __bf16* o_ws = (__bf16*)(ws + 19611648);      // aliases lgT (dead after k_coef)

  k_prep3<<<2880, 256, 0, stream>>>(x, Wv, Wa, Wp, xb, Wvt, Wat, Wpt);
  k_gemm1<0><<<dim3(392, 3), 256, 0, stream>>>(xb, Wvt, nullptr, v_ws);
  k_gemm1<1><<<dim3(392, 8), 256, 0, stream>>>(Wat, xb, ba, lgT);
  k_coef<<<dim3(98, 6), 256, 0, stream>>>(lgT, wcT);
  k_att2<<<NPIX / 8, 192, 0, stream>>>(v_ws, wcT, o_ws);
  k_gemm1<2><<<dim3(392, 3), 256, 0, stream>>>(o_ws, Wpt, bp, (float*)d_out);
}

// Round 9
// 137.417 us; speedup vs baseline: 1.1399x; 1.0651x over previous
//
#include <hip/hip_runtime.h>
#include <hip/hip_bf16.h>

// OutlookAttention: B=8,H=56,W=56,C=192,heads=6,K=3,pad=1 — fp32 in/out
constexpr int NH = 56, NW = 56, NC = 192, AJ = 486;
constexpr int HWP = NH * NW;   // 3136
constexpr int NPIX = 8 * HWP;  // 25088
constexpr float SCALE = 0.17677669529663687f;  // 1/sqrt(32)
constexpr int TS = 12288;  // elems per 64-row tile: 6 strips * 64 rows * 32 k

typedef __bf16 bf16x8 __attribute__((ext_vector_type(8)));
typedef float f32x4 __attribute__((ext_vector_type(4)));

__device__ __forceinline__ void gload16(const void* g, void* l) {
  __builtin_amdgcn_global_load_lds(
      (const __attribute__((address_space(1))) void*)g,
      (__attribute__((address_space(3))) void*)l, 16, 0, 0);
}

// tiled offset for (row, k) in a [tile64][strip6][row64][k32] operand
__device__ __forceinline__ size_t toff(int row, int k) {
  return (size_t)(row >> 6) * TS + (k >> 5) * 2048 + (row & 63) * 32 + (k & 31);
}

// ---------------------------------------------------------------------------
// P0: weights -> bf16 transposed [n][k] tiled (Wat padded to 512 rows);
//     x -> bf16 xb, tiled.
// ---------------------------------------------------------------------------
__global__ __launch_bounds__(256) void k_prep3(const float* __restrict__ x,
                                               const float* __restrict__ Wv,
                                               const float* __restrict__ Wa,
                                               const float* __restrict__ Wp,
                                               __bf16* __restrict__ xb,
                                               __bf16* __restrict__ Wvt,
                                               __bf16* __restrict__ Wat,
                                               __bf16* __restrict__ Wpt) {
  const int bid = blockIdx.x;
  if (bid < 144) {
    const int i = bid * 256 + threadIdx.x;
    const int n = i / 192, k = i - n * 192;
    const size_t d = toff(n, k);
    Wvt[d] = (__bf16)Wv[k * 192 + n];
    Wpt[d] = (__bf16)Wp[k * 192 + n];
  } else if (bid < 528) {
    const int i = (bid - 144) * 256 + threadIdx.x;
    const int n = i / 192, k = i - n * 192;
    Wat[toff(n, k)] = (n < 486) ? (__bf16)Wa[k * 486 + n] : (__bf16)0.f;
  } else {
    const size_t i = (size_t)(bid - 528) * 256 + threadIdx.x;
    const int pix = (int)(i / 24), c8 = (int)(i % 24) * 8;
    const float* src = x + (size_t)pix * 192 + c8;
    const float4 f0 = *(const float4*)src;
    const float4 f1 = *(const float4*)(src + 4);
    bf16x8 o8;
    o8[0] = (__bf16)f0.x; o8[1] = (__bf16)f0.y;
    o8[2] = (__bf16)f0.z; o8[3] = (__bf16)f0.w;
    o8[4] = (__bf16)f1.x; o8[5] = (__bf16)f1.y;
    o8[6] = (__bf16)f1.z; o8[7] = (__bf16)f1.w;
    *(bf16x8*)(xb + toff(pix, c8)) = o8;
  }
}

// ---------------------------------------------------------------------------
// Single-shot GEMM: 64x64 tile, whole K=192 staged once, one main barrier.
// MODE 0: v[pix][ch] bf16       (grid 392 x 3)  — LDS-coalesced epilogue
// MODE 1: lgT[j][pix] bf16      (grid 392 x 8)  — LDS-coalesced epilogue
// MODE 2: out[pix][ch] f32 + bp (grid 392 x 3)  — direct (64B segs ok)
// ---------------------------------------------------------------------------
template <int MODE>
__global__ __launch_bounds__(256) void k_gemm1(const __bf16* __restrict__ At,
                                               const __bf16* __restrict__ Bt,
                                               const float* __restrict__ bias,
                                               void* __restrict__ C) {
  __shared__ __bf16 As[64 * 192];
  __shared__ __bf16 Bs[64 * 192];
  const int t = threadIdx.x, lane = t & 63, w = t >> 6;
  const int wm = w >> 1, wn = w & 1;
  const int a_tile = (MODE == 1) ? blockIdx.y : blockIdx.x;
  const int b_tile = (MODE == 1) ? blockIdx.x : blockIdx.y;
  const __bf16* Asrc = At + (size_t)a_tile * TS;
  const __bf16* Bsrc = Bt + (size_t)b_tile * TS;
  #pragma unroll
  for (int i = 0; i < 6; ++i) {
    const int cb = i * 256 + w * 64;
    gload16(Asrc + (size_t)(cb + lane) * 8, &As[cb * 8]);
    gload16(Bsrc + (size_t)(cb + lane) * 8, &Bs[cb * 8]);
  }
  f32x4 acc[2][2];
  #pragma unroll
  for (int mi = 0; mi < 2; ++mi)
    #pragma unroll
    for (int nj = 0; nj < 2; ++nj) acc[mi][nj] = (f32x4){0.f, 0.f, 0.f, 0.f};
  __syncthreads();
  #pragma unroll
  for (int ks = 0; ks < 6; ++ks) {
    bf16x8 af[2], bfr[2];
    #pragma unroll
    for (int mi = 0; mi < 2; ++mi)
      af[mi] = *(const bf16x8*)&As[(ks * 64 + wm * 32 + mi * 16 + (lane & 15)) * 32 + (lane >> 4) * 8];
    #pragma unroll
    for (int nj = 0; nj < 2; ++nj)
      bfr[nj] = *(const bf16x8*)&Bs[(ks * 64 + wn * 32 + nj * 16 + (lane & 15)) * 32 + (lane >> 4) * 8];
    #pragma unroll
    for (int mi = 0; mi < 2; ++mi)
      #pragma unroll
      for (int nj = 0; nj < 2; ++nj)
        acc[mi][nj] = __builtin_amdgcn_mfma_f32_16x16x32_bf16(af[mi], bfr[nj], acc[mi][nj], 0, 0, 0);
  }
  const int col_l = lane & 15, rq4 = (lane >> 4) * 4;
  if (MODE == 2) {
    #pragma unroll
    for (int nj = 0; nj < 2; ++nj) {
      const int ln = wn * 32 + nj * 16 + col_l;
      const int ch = blockIdx.y * 64 + ln;
      const float bv = bias[ch];
      #pragma unroll
      for (int mi = 0; mi < 2; ++mi) {
        const int pix = blockIdx.x * 64 + wm * 32 + mi * 16 + rq4;
        #pragma unroll
        for (int r = 0; r < 4; ++r)
          ((float*)C)[(size_t)(pix + r) * 192 + ch] = acc[mi][nj][r] + bias[ch] - bv + bv;
      }
    }
    return;
  }
  // MODE 0/1: bounce C-tile through LDS (stride 72) for 128B-coalesced stores
  __bf16* Cs = As;  // reuse (dead after MFMA loop)
  __syncthreads();  // all ds_reads of As complete before overwrite
  #pragma unroll
  for (int nj = 0; nj < 2; ++nj) {
    const int ln = wn * 32 + nj * 16 + col_l;
    #pragma unroll
    for (int mi = 0; mi < 2; ++mi) {
      const int lmb = wm * 32 + mi * 16 + rq4;
      #pragma unroll
      for (int r = 0; r < 4; ++r) {
        float val = acc[mi][nj][r];
        if (MODE == 1) {
          const int j = blockIdx.y * 64 + lmb + r;
          val = (val + bias[j < 486 ? j : 0]) * SCALE;
        }
        Cs[(lmb + r) * 72 + ln] = (__bf16)val;
      }
    }
  }
  __syncthreads();
  {
    const int lm = t >> 2, seg = t & 3;  // 64 rows x 4 segments of 16
    const bf16x8 c0 = *(const bf16x8*)&Cs[lm * 72 + seg * 16];
    const bf16x8 c1 = *(const bf16x8*)&Cs[lm * 72 + seg * 16 + 8];
    if (MODE == 0) {
      const int pix = blockIdx.x * 64 + lm, ch = blockIdx.y * 64 + seg * 16;
      *(bf16x8*)&((__bf16*)C)[(size_t)pix * 192 + ch] = c0;
      *(bf16x8*)&((__bf16*)C)[(size_t)pix * 192 + ch + 8] = c1;
    } else {
      const int j = blockIdx.y * 64 + lm, pix = blockIdx.x * 64 + seg * 16;
      if (j < 486) {
        *(bf16x8*)&((__bf16*)C)[(size_t)j * NPIX + pix] = c0;
        *(bf16x8*)&((__bf16*)C)[(size_t)j * NPIX + pix + 8] = c1;
      }
    }
  }
}

// ---------------------------------------------------------------------------
// K-coef: fused softmax + delta-collapse. thread = dst pixel, blockIdx.y = head.
// ---------------------------------------------------------------------------
__global__ __launch_bounds__(256) void k_coef(const __bf16* __restrict__ lgT,
                                              __bf16* __restrict__ wcT) {
  const int p = blockIdx.x * 256 + threadIdx.x;
  const int head = blockIdx.y;
  const int b = p / HWP;
  const int yx = p - b * HWP;
  const int y = yx / NW, x = yx - y * NW;

  float wc[25];
  #pragma unroll
  for (int c = 0; c < 25; ++c) wc[c] = 0.f;

  #pragma unroll
  for (int ki = 0; ki < 3; ++ki) {
    const int h = y - ki + 1;
    if ((unsigned)h >= (unsigned)NH) continue;
    #pragma unroll
    for (int kj = 0; kj < 3; ++kj) {
      const int ww = x - kj + 1;
      if ((unsigned)ww >= (unsigned)NW) continue;
      const int src = b * HWP + h * NW + ww;
      const size_t base = (size_t)((head * 9 + ki * 3 + kj) * 9) * NPIX + src;
      float lt[9];
      #pragma unroll
      for (int l = 0; l < 9; ++l) lt[l] = (float)lgT[base + (size_t)l * NPIX];
      float m = lt[0];
      #pragma unroll
      for (int l = 1; l < 9; ++l) m = fmaxf(m, lt[l]);
      float s = 0.f;
      #pragma unroll
      for (int l = 0; l < 9; ++l) { lt[l] = __expf(lt[l] - m); s += lt[l]; }
      const float inv = 1.f / s;
      #pragma unroll
      for (int l = 0; l < 9; ++l) {
        const int li = l / 3, lj = l - li * 3;
        wc[(li - ki + 2) * 5 + (lj - kj + 2)] += lt[l] * inv;
      }
    }
  }
  #pragma unroll
  for (int c = 0; c < 25; ++c)
    wcT[(size_t)(head * 25 + c) * NPIX + p] = (__bf16)wc[c];
}

// ---------------------------------------------------------------------------
// K-att3: gather, 2-row x 8-col tiles (16 px) per block -> 4.5x halo over-read
// (was 7.5x at 8 px). 192 thr = channels. Writes o in k-strip tiled layout.
// ---------------------------------------------------------------------------
__global__ __launch_bounds__(192) void k_att3(const __bf16* __restrict__ v,
                                              const __bf16* __restrict__ wcT,
                                              __bf16* __restrict__ o) {
  const int bid = blockIdx.x;          // 7 * 28 * 8 = 1568
  const int cx = bid % 7;
  const int ry = (bid / 7) % 28;
  const int bb = bid / 196;
  const int y0 = ry * 2, x0 = cx * 8;
  const int p0 = bb * HWP + y0 * NW + x0;  // top row base (8-aligned)
  const int t = threadIdx.x;

  __shared__ __bf16 vs[72][192];   // rows y0-2..y0+3 x cols x0-2..x0+9; 27.6 KB
  __shared__ float wcs[16][6][28]; // 10.75 KB

  #pragma unroll
  for (int i = 0; i < 9; ++i) {  // 72 cells * 24 chunks = 1728 = 9*192
    const int u = i * 192 + t;
    const int cell = u / 24, ck = u - cell * 24;
    const int ri = cell / 12, ci = cell - ri * 12;
    const int yy = y0 + ri - 2, xx = x0 + ci - 2;
    bf16x8 val;
    #pragma unroll
    for (int j = 0; j < 8; ++j) val[j] = (__bf16)0.f;
    if ((unsigned)yy < (unsigned)NH && (unsigned)xx < (unsigned)NW)
      val = *(const bf16x8*)&v[(size_t)(bb * HWP + yy * NW + xx) * 192 + ck * 8];
    *(bf16x8*)&vs[cell][ck * 8] = val;
  }
  if (t < 150) {  // 150 (head,coef) rows x 16 px
    const int head = t / 25, cc = t - head * 25;
    const bf16x8 w0 = *(const bf16x8*)&wcT[(size_t)t * NPIX + p0];
    const bf16x8 w1 = *(const bf16x8*)&wcT[(size_t)t * NPIX + p0 + NW];
    #pragma unroll
    for (int q = 0; q < 8; ++q) {
      wcs[q][head][cc] = (float)w0[q];
      wcs[8 + q][head][cc] = (float)w1[q];
    }
  }
  __syncthreads();

  const int ch = t, head = ch >> 5;
  float vr[6][12];
  #pragma unroll
  for (int ri = 0; ri < 6; ++ri)
    #pragma unroll
    for (int ci = 0; ci < 12; ++ci) vr[ri][ci] = (float)vs[ri * 12 + ci][ch];
  #pragma unroll
  for (int q = 0; q < 16; ++q) {
    const int qr = q >> 3, qc = q & 7;
    float coef[25];
    #pragma unroll
    for (int i = 0; i < 6; ++i)
      *(float4*)&coef[i * 4] = *(const float4*)&wcs[q][head][i * 4];
    coef[24] = wcs[q][head][24];
    float s = 0.f;
    #pragma unroll
    for (int di = 0; di < 5; ++di)
      #pragma unroll
      for (int dj = 0; dj < 5; ++dj) s += coef[di * 5 + dj] * vr[qr + di][qc + dj];
    const int px = p0 + qr * NW + qc;
    o[toff(px, ch)] = (__bf16)s;
  }
}

// ---------------------------------------------------------------------------
extern "C" void kernel_launch(void* const* d_in, const int* in_sizes, int n_in,
                              void* d_out, int out_size, void* d_ws,
                              size_t ws_size, hipStream_t stream) {
  (void)in_sizes; (void)n_in; (void)out_size; (void)ws_size;
  const float* x  = (const float*)d_in[0];
  const float* Wv = (const float*)d_in[1];
  const float* Wa = (const float*)d_in[2];
  const float* ba = (const float*)d_in[3];
  const float* Wp = (const float*)d_in[4];
  const float* bp = (const float*)d_in[5];

  char* ws = (char*)d_ws;  // ws_size = 256 MiB; we use ~51.5 MB
  __bf16* Wvt = (__bf16*)(ws);                  //     73,728 B (tiled)
  __bf16* Wat = (__bf16*)(ws + 73728);          //    196,608 B (512x192 tiled)
  __bf16* Wpt = (__bf16*)(ws + 270336);         //     73,728 B (tiled)
  __bf16* xb  = (__bf16*)(ws + 344064);         //  9,633,792 B (tiled)
  __bf16* v_ws = (__bf16*)(ws + 9977856);       //  9,633,792 B (pixel-major)
  __bf16* lgT = (__bf16*)(ws + 19611648);       // 24,385,536 B (486 x 25088)
  __bf16* wcT = (__bf16*)(ws + 43997184);       //  7,526,400 B (150 x 25088)
  __bf16* o_ws = (__bf16*)(ws + 19611648);      // aliases lgT (dead after k_coef)

  k_prep3<<<2880, 256, 0, stream>>>(x, Wv, Wa, Wp, xb, Wvt, Wat, Wpt);
  k_gemm1<0><<<dim3(392, 3), 256, 0, stream>>>(xb, Wvt, nullptr, v_ws);
  k_gemm1<1><<<dim3(392, 8), 256, 0, stream>>>(Wat, xb, ba, lgT);
  k_coef<<<dim3(98, 6), 256, 0, stream>>>(lgT, wcT);
  k_att3<<<1568, 192, 0, stream>>>(v_ws, wcT, o_ws);
  k_gemm1<2><<<dim3(392, 3), 256, 0, stream>>>(o_ws, Wpt, bp, (float*)d_out);
}